// Round 6
// baseline (326.566 us; speedup 1.0000x reference)
//
#include <hip/hip_runtime.h>
#include <math.h>

#define KK 48
#define TT 1024
#define BB 512
#define START_TAG 46
#define END_TAG 47
#define NS 16            // sentences per block (mfma N dimension)
#define NBLK (BB / NS)   // 32 blocks
#define HT (TT / 2)      // 512 steps per direction
#define LSTR 28          // LDS column stride in dwords (breaks pow2 conflicts)

typedef float f32x4 __attribute__((ext_vector_type(4)));
typedef short short8 __attribute__((ext_vector_type(8)));
typedef unsigned u32x2 __attribute__((ext_vector_type(2)));
typedef unsigned u32x4 __attribute__((ext_vector_type(4)));

// pack two fp32 -> one dword of two bf16 (round-half-up via +0x8000)
__device__ __forceinline__ unsigned pack_bf16(float lo, float hi) {
    unsigned ul = __float_as_uint(lo) + 0x8000u;
    unsigned uh = __float_as_uint(hi) + 0x8000u;
    // result bytes: [ul.b2, ul.b3, uh.b2, uh.b3] = (uh>>16)<<16 | (ul>>16)
    return __builtin_amdgcn_perm(uh, ul, 0x07060302u);
}

// ---------------------------------------------------------------------------
// MFMA-batched bidirectional CRF neg-log-likelihood.
//
// 16 sentences per block as columns of X (48x16). Per step:
//   fwd: X' = (E @ X) * exp(F_t)        (wave 0, A = E bf16)
//   bwd: X' = E^T @ (X * exp(F_t))      (wave 1, A = E^T bf16)
// 6 mfma_f32_16x16x32_bf16 per step (3 M-tiles x 2 K-tiles, K padded 48->64).
// C-layout -> B-operand relayout via per-wave LDS (bf16 packed, col-major
// stride 28): 3 ds_write_b64 + 2 ds_read_b128 per step. Same-wave DS ordering
// means no barrier in the loop.
//
// Z_b = beta_m^T alpha_m at m=T/2 (R5-verified split). Per-column power-of-2
// rescale every 8 steps, exponent ledger per lane-group (uniform within the
// 4 lanes of a column). bf16 rounding error ~O(1) in log-space over 512
// steps; threshold is 90.24 absolute.
// ---------------------------------------------------------------------------
__global__ __launch_bounds__(128)
__attribute__((amdgpu_waves_per_eu(1, 1)))
void crf_kernel(const float* __restrict__ feats,
                const float* __restrict__ trans,
                const int* __restrict__ tags,
                float* __restrict__ out) {
    const int tid = threadIdx.x;
    const int wave = tid >> 6;       // 0 = fwd, 1 = bwd
    const int lane = tid & 63;
    const int n = lane & 15;         // column = sentence within block
    const int q = lane >> 4;         // quad 0..3
    const int blk = blockIdx.x;

    __shared__ __attribute__((aligned(16))) unsigned shX[2][NS * LSTR];
    __shared__ float shFin[2][64 * 12];
    __shared__ int shLed[2][NS];
    __shared__ float shGold[NS];

    // ---- A fragments: E (fwd) / E^T (bwd), bf16. A[m=lane&15][k=q*8+j] ----
    short8 A[3][2];
    #pragma unroll
    for (int mt = 0; mt < 3; ++mt) {
        #pragma unroll
        for (int kt = 0; kt < 2; ++kt) {
            short8 f = {};
            #pragma unroll
            for (int j = 0; j < 8; ++j) {
                int m = mt * 16 + n;
                int k = kt * 32 + q * 8 + j;
                float v = 0.0f;
                if (k < KK)
                    v = __expf(wave == 0 ? trans[m * KK + k] : trans[k * KK + m]);
                unsigned u = __float_as_uint(v) + 0x8000u;
                f[j] = (short)(u >> 16);
            }
            A[mt][kt] = f;
        }
    }

    unsigned* lb = &shX[wave][0];
    const float* fb = feats + ((size_t)(blk * NS + n) * TT) * KK + 4 * q;

    f32x4 X[3];          // C-layout state: X[mt][r] = row mt*16+4q+r, col n
    f32x4 ring[4][3];    // 4-step raw-feats prefetch ring
    int led = 0;         // power-of-2 exponent ledger (uniform per column)

    if (wave == 0) {
        // ======================= FORWARD =======================
        // X_0 = e_START indicator: B-layout row 46 -> kt1, q==1, j==6
        short8 B0 = {}, B1 = {};
        if (q == 1) B1[6] = (short)0x3F80;   // bf16(1.0)

        #pragma unroll
        for (int s = 0; s < 4; ++s)
            #pragma unroll
            for (int mt = 0; mt < 3; ++mt)
                ring[s][mt] = *(const f32x4*)(fb + (size_t)s * KK + 16 * mt);

        #pragma unroll 4
        for (int t = 0; t < HT; ++t) {
            // D = E @ X
            f32x4 D[3];
            #pragma unroll
            for (int mt = 0; mt < 3; ++mt) {
                f32x4 c = {0.f, 0.f, 0.f, 0.f};
                c = __builtin_amdgcn_mfma_f32_16x16x32_bf16(A[mt][0], B0, c, 0, 0, 0);
                c = __builtin_amdgcn_mfma_f32_16x16x32_bf16(A[mt][1], B1, c, 0, 0, 0);
                D[mt] = c;
            }
            // X = D * exp(feat_t), refill ring with row t+4 (over-read safe)
            int sl = t & 3;
            #pragma unroll
            for (int mt = 0; mt < 3; ++mt) {
                f32x4 r = ring[sl][mt];
                X[mt][0] = D[mt][0] * __expf(r[0]);
                X[mt][1] = D[mt][1] * __expf(r[1]);
                X[mt][2] = D[mt][2] * __expf(r[2]);
                X[mt][3] = D[mt][3] * __expf(r[3]);
                ring[sl][mt] = *(const f32x4*)(fb + (size_t)(t + 4) * KK + 16 * mt);
            }
            // per-column rescale every 8 steps
            if ((t & 7) == 7) {
                float m = X[0][0];
                #pragma unroll
                for (int mt = 0; mt < 3; ++mt) {
                    m = fmaxf(m, X[mt][0]); m = fmaxf(m, X[mt][1]);
                    m = fmaxf(m, X[mt][2]); m = fmaxf(m, X[mt][3]);
                }
                m = fmaxf(m, __shfl_xor(m, 16, 64));
                m = fmaxf(m, __shfl_xor(m, 32, 64));
                int e0 = ((__float_as_int(m) >> 23) & 0xff) - 127;
                led += e0;
                float sc = __int_as_float((127 - e0) << 23);
                #pragma unroll
                for (int mt = 0; mt < 3; ++mt) {
                    X[mt][0] *= sc; X[mt][1] *= sc;
                    X[mt][2] *= sc; X[mt][3] *= sc;
                }
            }
            // pack -> LDS -> B-operand layout
            #pragma unroll
            for (int mt = 0; mt < 3; ++mt) {
                u32x2 p;
                p.x = pack_bf16(X[mt][0], X[mt][1]);
                p.y = pack_bf16(X[mt][2], X[mt][3]);
                *(u32x2*)(lb + n * LSTR + mt * 8 + 2 * q) = p;
            }
            u32x4 t0 = *(const u32x4*)(lb + n * LSTR + 4 * q);
            u32x4 t1 = *(const u32x4*)(lb + n * LSTR + 16 + 4 * (q & 1));
            if (q >= 2) { t1.x = 0; t1.y = 0; t1.z = 0; t1.w = 0; }
            B0 = __builtin_bit_cast(short8, t0);
            B1 = __builtin_bit_cast(short8, t1);
        }
    } else {
        // ======================= BACKWARD =======================
        // beta_T = exp(trans[END][i]) in C-layout
        #pragma unroll
        for (int mt = 0; mt < 3; ++mt) {
            #pragma unroll
            for (int r = 0; r < 4; ++r)
                X[mt][r] = __expf(trans[END_TAG * KK + (mt * 16 + 4 * q + r)]);
        }
        #pragma unroll
        for (int s = 0; s < 4; ++s)
            #pragma unroll
            for (int mt = 0; mt < 3; ++mt)
                ring[s][mt] = *(const f32x4*)(fb + (size_t)(TT - 1 - s) * KK + 16 * mt);

        #pragma unroll 4
        for (int t = 0; t < HT; ++t) {
            // W = X * exp(feat_{1023-t}), refill ring with row 1019-t
            int sl = t & 3;
            f32x4 W[3];
            #pragma unroll
            for (int mt = 0; mt < 3; ++mt) {
                f32x4 r = ring[sl][mt];
                W[mt][0] = X[mt][0] * __expf(r[0]);
                W[mt][1] = X[mt][1] * __expf(r[1]);
                W[mt][2] = X[mt][2] * __expf(r[2]);
                W[mt][3] = X[mt][3] * __expf(r[3]);
                ring[sl][mt] = *(const f32x4*)(fb + (size_t)(TT - 5 - t) * KK + 16 * mt);
            }
            if ((t & 7) == 7) {
                float m = W[0][0];
                #pragma unroll
                for (int mt = 0; mt < 3; ++mt) {
                    m = fmaxf(m, W[mt][0]); m = fmaxf(m, W[mt][1]);
                    m = fmaxf(m, W[mt][2]); m = fmaxf(m, W[mt][3]);
                }
                m = fmaxf(m, __shfl_xor(m, 16, 64));
                m = fmaxf(m, __shfl_xor(m, 32, 64));
                int e0 = ((__float_as_int(m) >> 23) & 0xff) - 127;
                led += e0;
                float sc = __int_as_float((127 - e0) << 23);
                #pragma unroll
                for (int mt = 0; mt < 3; ++mt) {
                    W[mt][0] *= sc; W[mt][1] *= sc;
                    W[mt][2] *= sc; W[mt][3] *= sc;
                }
            }
            // pack -> LDS -> B, then X = E^T @ W
            #pragma unroll
            for (int mt = 0; mt < 3; ++mt) {
                u32x2 p;
                p.x = pack_bf16(W[mt][0], W[mt][1]);
                p.y = pack_bf16(W[mt][2], W[mt][3]);
                *(u32x2*)(lb + n * LSTR + mt * 8 + 2 * q) = p;
            }
            u32x4 t0 = *(const u32x4*)(lb + n * LSTR + 4 * q);
            u32x4 t1 = *(const u32x4*)(lb + n * LSTR + 16 + 4 * (q & 1));
            if (q >= 2) { t1.x = 0; t1.y = 0; t1.z = 0; t1.w = 0; }
            short8 B0 = __builtin_bit_cast(short8, t0);
            short8 B1 = __builtin_bit_cast(short8, t1);
            #pragma unroll
            for (int mt = 0; mt < 3; ++mt) {
                f32x4 c = {0.f, 0.f, 0.f, 0.f};
                c = __builtin_amdgcn_mfma_f32_16x16x32_bf16(A[mt][0], B0, c, 0, 0, 0);
                c = __builtin_amdgcn_mfma_f32_16x16x32_bf16(A[mt][1], B1, c, 0, 0, 0);
                X[mt] = c;
            }
        }
    }

    // ---- dump final state + ledgers ----
    #pragma unroll
    for (int mt = 0; mt < 3; ++mt)
        #pragma unroll
        for (int r = 0; r < 4; ++r)
            shFin[wave][lane * 12 + mt * 4 + r] = X[mt][r];
    if (lane < NS) shLed[wave][lane] = led;   // lane<16 is the q==0 lane of col=lane

    // ---- gold score: sentence s = tid/8, t-chunk c = tid%8 ----
    {
        int s = tid >> 3;
        int c = tid & 7;
        const int* tg = tags + (size_t)(blk * NS + s) * TT;
        const float* fs = feats + (size_t)(blk * NS + s) * TT * KK;
        float g = 0.0f;
        int tbeg = c * 128;
        #pragma unroll 4
        for (int t = tbeg; t < tbeg + 128; ++t) {
            int cur = tg[t];
            int prev = (t == 0) ? START_TAG : tg[t - 1];
            g += trans[cur * KK + prev] + fs[(size_t)t * KK + cur];
        }
        if (c == 0) g += trans[END_TAG * KK + tg[TT - 1]];
        g += __shfl_xor(g, 1, 64);
        g += __shfl_xor(g, 2, 64);
        g += __shfl_xor(g, 4, 64);
        if (c == 0) shGold[s] = g;
    }

    __syncthreads();

    // ---- combine: Z_b = sum_i alpha[i]*beta[i], out = logZ - gold ----
    if (wave == 0 && lane < NS) {
        float dot = 0.0f;
        #pragma unroll
        for (int r = 0; r < KK; ++r) {
            int src = (((r & 15) >> 2) << 4) + lane;   // lane holding row r, col=lane
            int idx = src * 12 + (r >> 4) * 4 + (r & 3);
            dot += shFin[0][idx] * shFin[1][idx];
        }
        float logz = logf(dot) +
                     (float)(shLed[0][lane] + shLed[1][lane]) * 0.6931471805599453f;
        out[blk * NS + lane] = logz - shGold[lane];
    }
}

extern "C" void kernel_launch(void* const* d_in, const int* in_sizes, int n_in,
                              void* d_out, int out_size, void* d_ws, size_t ws_size,
                              hipStream_t stream) {
    const float* feats = (const float*)d_in[0];
    const float* trans = (const float*)d_in[1];
    const int* tags = (const int*)d_in[2];
    float* out = (float*)d_out;

    crf_kernel<<<NBLK, 128, 0, stream>>>(feats, trans, tags, out);
}

// Round 7
// 274.306 us; speedup vs baseline: 1.1905x; 1.1905x over previous
//
#include <hip/hip_runtime.h>
#include <math.h>

#define KK 48
#define TT 1024
#define BB 512
#define START_TAG 46
#define END_TAG 47
#define HGRP (TT / 2 / 4)   // 128 groups of 4 steps per half

// ---------------------------------------------------------------------------
// Bidirectional CRF neg-log-likelihood, TWO waves per sentence (R5 structure).
//
//   Z = beta_m^T * alpha_m   (exact for any split m; m = T/2)
//   alpha_t = diag(ef_t) E alpha_{t-1}        (wave 0, feats rows 0..511)
//   beta_{t-1} = E^T diag(ef_t) beta_t        (wave 1, feats rows 1023..512)
//
// R6 lesson: per-step LDS round-trips (write->read, MFMA relayout) cost more
// than they save — the serial chain tolerates only register-file latency.
// R5 ran at 787 cyc/step with only ~315 cyc of VALU issue; the ~470-cyc gap
// is dependency stall. R7 attacks it:
//   (1) 8 accumulator chains (dep depth 12 -> 6),
//   (2) sched_barrier fences so the 48 readlanes form one contiguous block
//       and every readlane's consumer sits >= 47 instructions later,
//   (3) 3-level reduction tree.
// amdgpu_waves_per_eu(1,1) (max=1) keeps the full VGPR budget (R4 lesson).
//
// Uniform power-of-2 rescale every 4 steps, exact int exponent ledger
// (absmax 0.0 in R1-R5). exp(-1e5)==0 masks START-row/END-col for free.
// ---------------------------------------------------------------------------

template <bool FWD>
__device__ __forceinline__ void run_half(const float* __restrict__ fb,
                                         const float* __restrict__ trans,
                                         int ci, float& sOut, int& esumOut) {
    // E for this direction: fwd needs row ci of exp(trans), bwd needs col ci
    float Ew[KK];
    #pragma unroll
    for (int j = 0; j < KK; ++j)
        Ew[j] = __expf(FWD ? trans[ci * KK + j] : trans[j * KK + ci]);

    // lane-local state + wave-uniform broadcast state
    float s = FWD ? 0.0f : __expf(trans[END_TAG * KK + ci]);  // beta_T[ci]
    float au[KK];
    #pragma unroll
    for (int j = 0; j < KK; ++j) au[j] = (j == START_TAG) ? 1.0f : 0.0f;

    int esum = 0;

    // feats prefetch: groups of 4 rows; fwd ascending, bwd descending
    float fr[4];
    #pragma unroll
    for (int k = 0; k < 4; ++k) {
        int row = FWD ? k : (TT - 1 - k);
        fr[k] = fb[row * KK + ci];
    }

    for (int g = 0; g < HGRP; ++g) {
        float fn[4] = {0.f, 0.f, 0.f, 0.f};
        if (g < HGRP - 1) {
            #pragma unroll
            for (int k = 0; k < 4; ++k) {
                int row = FWD ? ((g + 1) * 4 + k) : (TT - 1 - (g + 1) * 4 - k);
                fn[k] = fb[row * KK + ci];
            }
        }
        // exp(feat) for current group — raw values loaded a full group ago
        float ef[4];
        #pragma unroll
        for (int k = 0; k < 4; ++k) ef[k] = __expf(fr[k]);

        #pragma unroll
        for (int k = 0; k < 4; ++k) {
            if (FWD) {
                // s_i = sum_j E[i,j] au[j] : 8 independent chains, 6 deep
                float a0 = 0.f, a1 = 0.f, a2 = 0.f, a3 = 0.f;
                float a4 = 0.f, a5 = 0.f, a6 = 0.f, a7 = 0.f;
                #pragma unroll
                for (int c = 0; c < 6; ++c) {
                    a0 = fmaf(Ew[8 * c + 0], au[8 * c + 0], a0);
                    a1 = fmaf(Ew[8 * c + 1], au[8 * c + 1], a1);
                    a2 = fmaf(Ew[8 * c + 2], au[8 * c + 2], a2);
                    a3 = fmaf(Ew[8 * c + 3], au[8 * c + 3], a3);
                    a4 = fmaf(Ew[8 * c + 4], au[8 * c + 4], a4);
                    a5 = fmaf(Ew[8 * c + 5], au[8 * c + 5], a5);
                    a6 = fmaf(Ew[8 * c + 6], au[8 * c + 6], a6);
                    a7 = fmaf(Ew[8 * c + 7], au[8 * c + 7], a7);
                }
                s = (((a0 + a1) + (a2 + a3)) + ((a4 + a5) + (a6 + a7))) * ef[k];
                if (k == 1) {   // uniform rescale; au[0] > 0 from step 1 on
                    int e0 = ((__float_as_int(au[0]) >> 23) & 0xff) - 127;
                    esum += e0;
                    s *= __int_as_float((127 - e0) << 23);
                }
                // --- contiguous readlane block, fenced ---
                __builtin_amdgcn_sched_barrier(0);
                int sb = __float_as_int(s);
                #pragma unroll
                for (int j = 0; j < KK; ++j)
                    au[j] = __int_as_float(__builtin_amdgcn_readlane(sb, j));
                __builtin_amdgcn_sched_barrier(0);
            } else {
                // w = s*ef; broadcast w;  s_i = sum_j E[j,i] au[j]
                float w = s * ef[k];
                if (k == 1) {   // uniform rescale; au[0] > 0 from step 1 on
                    int e0 = ((__float_as_int(au[0]) >> 23) & 0xff) - 127;
                    esum += e0;
                    w *= __int_as_float((127 - e0) << 23);
                }
                __builtin_amdgcn_sched_barrier(0);
                int wb = __float_as_int(w);
                #pragma unroll
                for (int j = 0; j < KK; ++j)
                    au[j] = __int_as_float(__builtin_amdgcn_readlane(wb, j));
                __builtin_amdgcn_sched_barrier(0);
                float a0 = 0.f, a1 = 0.f, a2 = 0.f, a3 = 0.f;
                float a4 = 0.f, a5 = 0.f, a6 = 0.f, a7 = 0.f;
                #pragma unroll
                for (int c = 0; c < 6; ++c) {
                    a0 = fmaf(Ew[8 * c + 0], au[8 * c + 0], a0);
                    a1 = fmaf(Ew[8 * c + 1], au[8 * c + 1], a1);
                    a2 = fmaf(Ew[8 * c + 2], au[8 * c + 2], a2);
                    a3 = fmaf(Ew[8 * c + 3], au[8 * c + 3], a3);
                    a4 = fmaf(Ew[8 * c + 4], au[8 * c + 4], a4);
                    a5 = fmaf(Ew[8 * c + 5], au[8 * c + 5], a5);
                    a6 = fmaf(Ew[8 * c + 6], au[8 * c + 6], a6);
                    a7 = fmaf(Ew[8 * c + 7], au[8 * c + 7], a7);
                }
                s = ((a0 + a1) + (a2 + a3)) + ((a4 + a5) + (a6 + a7));
            }
        }
        #pragma unroll
        for (int k = 0; k < 4; ++k) fr[k] = fn[k];
    }
    sOut = s;        // fwd: alpha_512[lane];  bwd: beta_512[lane]
    esumOut = esum;
}

__global__ __launch_bounds__(128)
__attribute__((amdgpu_waves_per_eu(1, 1)))
void crf_kernel(const float* __restrict__ feats,
                const float* __restrict__ trans,
                const int* __restrict__ tags,
                float* __restrict__ out) {
    const int b = blockIdx.x;
    const int tid = threadIdx.x;
    const int wave = tid >> 6;          // 0 = forward, 1 = backward
    const int lane = tid & 63;
    const int ci = (lane < KK) ? lane : 0;
    const float* fb = feats + (size_t)b * TT * KK;
    const int* tg = tags + b * TT;

    __shared__ float sh[128];
    __shared__ int shE[2];
    __shared__ float shG[2];

    float sLast; int esum;
    if (wave == 0) run_half<true>(fb, trans, ci, sLast, esum);
    else           run_half<false>(fb, trans, ci, sLast, esum);

    sh[tid] = sLast;
    if (lane == 0) shE[wave] = esum;

    // ---- gold gather: 1024 t's over 128 threads, after the hot loop ----
    float gacc = 0.0f;
    #pragma unroll
    for (int r = 0; r < TT / 128; ++r) {
        int t = tid + r * 128;
        int cur = tg[t];
        int prev = (t == 0) ? START_TAG : tg[t - 1];
        gacc += trans[cur * KK + prev] + fb[t * KK + cur];
    }
    #pragma unroll
    for (int off = 32; off; off >>= 1) gacc += __shfl_xor(gacc, off, 64);
    if (lane == 0) shG[wave] = gacc;

    __syncthreads();

    if (wave == 0) {
        // Z = sum_i alpha_m[i] * beta_m[i]   (exponent ledgers add)
        float val = (lane < KK) ? sh[lane] * sh[64 + lane] : 0.0f;
        #pragma unroll
        for (int off = 32; off; off >>= 1) val += __shfl_xor(val, off, 64);
        if (lane == 0) {
            float logz = __logf(val) +
                         (float)(shE[0] + shE[1]) * 0.6931471805599453f;
            float gold = shG[0] + shG[1] + trans[END_TAG * KK + tg[TT - 1]];
            out[b] = logz - gold;
        }
    }
}

extern "C" void kernel_launch(void* const* d_in, const int* in_sizes, int n_in,
                              void* d_out, int out_size, void* d_ws, size_t ws_size,
                              hipStream_t stream) {
    const float* feats = (const float*)d_in[0];
    const float* trans = (const float*)d_in[1];
    const int* tags = (const int*)d_in[2];
    float* out = (float*)d_out;

    crf_kernel<<<BB, 128, 0, stream>>>(feats, trans, tags, out);
}